// Round 2
// baseline (390.896 us; speedup 1.0000x reference)
//
#include <hip/hip_runtime.h>
#include <stdint.h>

typedef unsigned long long u64;
typedef unsigned int u32;

#define N_IMG 32
#define C_IN  256
#define C_OUT 256
#define H     56
#define W     56
#define HW    (H*W)          // 3136
#define NHW   (N_IMG*HW)     // 100352
#define CHW   (C_IN*HW)      // 802816

// Workspace layout:
//   px: [n][h][w][4] u64 packed sign bits of x      (401408 * 8 = 3,211,264 B)
//   pw: [co][tap(9)][4] u64                         (9216   * 8 =    73,728 B)
//   y : [n][co][h][w] int16 exact conv result       (25,690,112 * 2 = 51,380,224 B)
//   partials: overlaps px (px dead after conv) — [8192][2] long long = 131,072 B
#define PX_BYTES 3211264
#define PW_BYTES 73728

// ---------------------------------------------------------------------------
// Pack activations, 4 pixels per thread via float4. bit=1 <=> sign(x)==-1.
// t -> (n, h, word, w4): lanes consecutive in w4 -> 1KB/wave coalesced loads.
// ---------------------------------------------------------------------------
__global__ __launch_bounds__(256)
void pack_x_kernel(const float* __restrict__ x, u64* __restrict__ px) {
    int t = blockIdx.x * 256 + threadIdx.x;   // [0, 32*56*4*14) = 100352
    int w4   = t % 14;
    int r    = t / 14;
    int word = r & 3;
    int r2   = r >> 2;
    int h    = r2 % H;
    int n    = r2 / H;
    const float4* src = (const float4*)(x + ((size_t)(n*C_IN + word*64) * HW + h*W + w4*4));
    u64 b0 = 0, b1 = 0, b2 = 0, b3 = 0;
    #pragma unroll 8
    for (int j = 0; j < 64; ++j) {
        float4 v = src[(size_t)j * (HW/4)];
        b0 |= (u64)(__float_as_uint(v.x) >> 31) << j;
        b1 |= (u64)(__float_as_uint(v.y) >> 31) << j;
        b2 |= (u64)(__float_as_uint(v.z) >> 31) << j;
        b3 |= (u64)(__float_as_uint(v.w) >> 31) << j;
    }
    u64* dst = px + (((size_t)((n*H + h)*W + w4*4)) << 2) + word;
    dst[0] = b0; dst[4] = b1; dst[8] = b2; dst[12] = b3;
}

// ---------------------------------------------------------------------------
// Pack weights: pw[co][tap][word], tap = kh*3+kw, bit c%64 of word c/64.
// ---------------------------------------------------------------------------
__global__ __launch_bounds__(256)
void pack_w_kernel(const float* __restrict__ wt, u64* __restrict__ pw) {
    int t = blockIdx.x * 256 + threadIdx.x;   // [0, 256*9*4) = 9216
    int word = t & 3;
    int tap  = (t >> 2) % 9;
    int co   = t / 36;
    int kh = tap / 3, kw = tap % 3;
    u64 bits = 0;
    for (int j = 0; j < 64; ++j) {
        int c = word*64 + j;
        float v = wt[((size_t)(co*C_IN + c) * 9) + kh*3 + kw];
        bits |= (u64)(__float_as_uint(v) >> 31) << j;
    }
    pw[t] = bits;   // t == (co*9 + tap)*4 + word
}

// ---------------------------------------------------------------------------
// XNOR-popcount conv. 36 tap words in EXPLICIT named registers.
//
// VGPR fix round 3. History:
//   R-1: u64[36] array -> scratch demotion (VGPR=56, 7.4 GB scratch traffic).
//   R0:  named regs, but allocator REMATERIALIZED the px loads inside the
//        ci loop (VGPR=64 < 72 needed) -> ~18 dwordx4/ci/wave through L1
//        -> L1-port bound (~188 us model vs 167 us measured).
//   R1:  launch_bounds(256,4) + asm memory clobber: FAILED, VGPR still 64.
//        Cause: px is const __restrict__, so the loads are provably
//        invariant -> re-loading after a "memory" clobber is still legal.
//   R2 (this): pin each x-word as the OUTPUT of an opaque inline asm
//        ("+v" tie). A value defined by volatile asm cannot be recomputed
//        by re-loading memory -> the 36 u64 (72 VGPRs) must stay resident.
//        launch_bounds(256,4) keeps the cap at 128 so nothing spills.
//
// Padding taps: clamped-address load + per-tap mask m_t (-1/0):
// acc = 128*n_invalid + sum(pc_t & m_t). Weights read with wave-uniform
// addresses -> s_load broadcast into SGPRs, no LDS.
// ---------------------------------------------------------------------------
__global__ __launch_bounds__(256, 4)
void conv_kernel(const u64* __restrict__ px, const u64* __restrict__ pw,
                 short* __restrict__ y) {
    int p = blockIdx.x * 256 + threadIdx.x;   // [0, 100352)
    int n = p / HW;
    int r = p % HW;
    int h = r / W;
    int w = r % W;
    int cobase = blockIdx.y * 64;

    int acc0 = 0;

#define LOADTAP(T, KH, KW)                                                  \
    u64 xa##T, xb##T, xc##T, xd##T; int m##T;                               \
    {                                                                       \
        int hh = h + (KH) - 1, ww = w + (KW) - 1;                           \
        bool ok = ((unsigned)hh < (unsigned)H) && ((unsigned)ww < (unsigned)W); \
        int hc = ok ? hh : 0, wc = ok ? ww : 0;                             \
        const u64* s = px + (((size_t)((n*H + hc)*W + wc)) << 2);           \
        xa##T = s[0]; xb##T = s[1]; xc##T = s[2]; xd##T = s[3];             \
        m##T = ok ? -1 : 0;                                                 \
        acc0 += ok ? 0 : 128;                                               \
    }

    LOADTAP(0, 0, 0) LOADTAP(1, 0, 1) LOADTAP(2, 0, 2)
    LOADTAP(3, 1, 0) LOADTAP(4, 1, 1) LOADTAP(5, 1, 2)
    LOADTAP(6, 2, 0) LOADTAP(7, 2, 1) LOADTAP(8, 2, 2)
#undef LOADTAP

    // Pin all 36 x-words into VGPRs: each value becomes the output of an
    // opaque volatile asm, which the compiler CANNOT rematerialize by
    // re-loading px (the R0/R1 failure mode). 3 statements x 12 operands
    // to stay under inline-asm operand limits.
    asm volatile("" : "+v"(xa0), "+v"(xb0), "+v"(xc0), "+v"(xd0),
                      "+v"(xa1), "+v"(xb1), "+v"(xc1), "+v"(xd1),
                      "+v"(xa2), "+v"(xb2), "+v"(xc2), "+v"(xd2));
    asm volatile("" : "+v"(xa3), "+v"(xb3), "+v"(xc3), "+v"(xd3),
                      "+v"(xa4), "+v"(xb4), "+v"(xc4), "+v"(xd4),
                      "+v"(xa5), "+v"(xb5), "+v"(xc5), "+v"(xd5));
    asm volatile("" : "+v"(xa6), "+v"(xb6), "+v"(xc6), "+v"(xd6),
                      "+v"(xa7), "+v"(xb7), "+v"(xc7), "+v"(xd7),
                      "+v"(xa8), "+v"(xb8), "+v"(xc8), "+v"(xd8));

    const u64* wq = pw + (size_t)cobase * 36;
    short* yout = y + (size_t)n*CHW + (size_t)cobase*HW + r;

    for (int ci = 0; ci < 64; ++ci) {
        const u64* q = wq + ci*36;   // wave-uniform -> scalar loads
        int acc = acc0;
#define TAP(T)                                                              \
        {                                                                   \
            int pc = __popcll(xa##T ^ q[(T)*4+0])                           \
                   + __popcll(xb##T ^ q[(T)*4+1])                           \
                   + __popcll(xc##T ^ q[(T)*4+2])                           \
                   + __popcll(xd##T ^ q[(T)*4+3]);                          \
            acc += pc & m##T;                                               \
        }
        TAP(0) TAP(1) TAP(2) TAP(3) TAP(4) TAP(5) TAP(6) TAP(7) TAP(8)
#undef TAP
        yout[(size_t)ci * HW] = (short)(2304 - 2*acc);
    }
}

// ---------------------------------------------------------------------------
// Stats pass: one block per (n,co) slab (3136 contiguous shorts), int4 loads
// (8 shorts), block-reduce, write per-slab partials (no atomics, no memset).
// ---------------------------------------------------------------------------
__global__ __launch_bounds__(256)
void stats_kernel(const short* __restrict__ y, long long* __restrict__ partials) {
    int slab = blockIdx.x;                    // n*256 + co
    const int4* ys = (const int4*)(y + (size_t)slab * HW);
    int s = 0, sq = 0;                        // per-thread <=16 vals: int32-safe
    for (int i = threadIdx.x; i < HW/8; i += 256) {   // 392 int4 per slab
        int4 v = ys[i];
        int vv[4] = {v.x, v.y, v.z, v.w};
        #pragma unroll
        for (int k = 0; k < 4; ++k) {
            int lo = (short)(vv[k] & 0xFFFF);
            int hi = (short)(vv[k] >> 16);
            s  += lo + hi;
            sq += lo*lo + hi*hi;
        }
    }
    __shared__ int       rs[256];
    __shared__ long long rq[256];
    rs[threadIdx.x] = s;
    rq[threadIdx.x] = sq;
    __syncthreads();
    for (int off = 128; off > 0; off >>= 1) {
        if (threadIdx.x < off) {
            rs[threadIdx.x] += rs[threadIdx.x + off];
            rq[threadIdx.x] += rq[threadIdx.x + off];
        }
        __syncthreads();
    }
    if (threadIdx.x == 0) {
        partials[2*slab]   = rs[0];
        partials[2*slab+1] = rq[0];
    }
}

// ---------------------------------------------------------------------------
// Apply pass: one block per (n,co) slab. Reduce the 32 per-image partials of
// this channel (uniform scalar loads), compute a,b, vectorized normalize.
// ---------------------------------------------------------------------------
__global__ __launch_bounds__(256)
void apply_kernel(const short* __restrict__ y, const long long* __restrict__ partials,
                  const float* __restrict__ gamma, const float* __restrict__ beta,
                  float* __restrict__ out) {
    int slab = blockIdx.x;
    int co = slab & 255;
    long long S = 0, SS = 0;
    #pragma unroll 8
    for (int m = 0; m < N_IMG; ++m) {
        S  += partials[2*((m<<8) | co)];
        SS += partials[2*((m<<8) | co) + 1];
    }
    double mean = (double)S  * (1.0 / (double)NHW);
    double var  = (double)SS * (1.0 / (double)NHW) - mean*mean;
    float a = gamma[co] * rsqrtf((float)var + 1e-5f);
    float b = beta[co] - (float)mean * a;

    const int4* ys = (const int4*)(y + (size_t)slab * HW);
    float4*     os = (float4*)(out + (size_t)slab * HW);
    for (int i = threadIdx.x; i < HW/8; i += 256) {
        int4 v = ys[i];
        float4 f0, f1;
        f0.x = a * (float)((short)(v.x & 0xFFFF)) + b;
        f0.y = a * (float)((short)(v.x >> 16))    + b;
        f0.z = a * (float)((short)(v.y & 0xFFFF)) + b;
        f0.w = a * (float)((short)(v.y >> 16))    + b;
        f1.x = a * (float)((short)(v.z & 0xFFFF)) + b;
        f1.y = a * (float)((short)(v.z >> 16))    + b;
        f1.z = a * (float)((short)(v.w & 0xFFFF)) + b;
        f1.w = a * (float)((short)(v.w >> 16))    + b;
        os[2*i]   = f0;
        os[2*i+1] = f1;
    }
}

// ---------------------------------------------------------------------------
extern "C" void kernel_launch(void* const* d_in, const int* in_sizes, int n_in,
                              void* d_out, int out_size, void* d_ws, size_t ws_size,
                              hipStream_t stream) {
    const float* x     = (const float*)d_in[0];
    const float* wt    = (const float*)d_in[1];
    const float* gamma = (const float*)d_in[2];
    const float* beta  = (const float*)d_in[3];
    float* out = (float*)d_out;

    char* ws = (char*)d_ws;
    u64*   px = (u64*)ws;
    u64*   pw = (u64*)(ws + PX_BYTES);
    short* y  = (short*)(ws + PX_BYTES + PW_BYTES);
    long long* partials = (long long*)ws;   // overlaps px: px dead after conv

    hipLaunchKernelGGL(pack_x_kernel, dim3(100352/256), dim3(256), 0, stream, x, px);
    hipLaunchKernelGGL(pack_w_kernel, dim3(9216/256),   dim3(256), 0, stream, wt, pw);
    hipLaunchKernelGGL(conv_kernel,   dim3(392, 4),     dim3(256), 0, stream, px, pw, y);
    hipLaunchKernelGGL(stats_kernel,  dim3(8192),       dim3(256), 0, stream, y, partials);
    hipLaunchKernelGGL(apply_kernel,  dim3(8192),       dim3(256), 0, stream, y, partials, gamma, beta, out);
}

// Round 3
// 370.678 us; speedup vs baseline: 1.0545x; 1.0545x over previous
//
#include <hip/hip_runtime.h>
#include <stdint.h>

typedef unsigned long long u64;
typedef unsigned int u32;

#define N_IMG 32
#define C_IN  256
#define C_OUT 256
#define H     56
#define W     56
#define HW    (H*W)          // 3136
#define NHW   (N_IMG*HW)     // 100352
#define CHW   (C_IN*HW)      // 802816

// Workspace layout (px padded by 2KB front/back so the main conv can issue
// clamp-free tap loads with immediate offsets in [-1824, +1824] without
// faulting; garbage values land only in border pixels, which a dedicated
// border kernel overwrites):
//   [0,2048)                      front pad (also start of partials overlap)
//   px  @ 2048: [n][h][w][4] u64  (401408 * 8 = 3,211,264 B)
//   rear pad 2048
//   pw2 @ 2048+PX+2048: [word][co][tap] u64  (9216 * 8 = 73,728 B)
//   y   @ ...: [n][co][h][w] int16            (51,380,224 B)
//   partials overlaps px region (px dead after conv+border)
#define PX_BYTES 3211264
#define PW_BYTES 73728
#define PX_OFF   2048
#define PW_OFF   (PX_OFF + PX_BYTES + 2048)
#define Y_OFF    (PW_OFF + PW_BYTES)

// ---------------------------------------------------------------------------
// Pack activations, 4 pixels per thread via float4. bit=1 <=> sign(x)==-1.
// ---------------------------------------------------------------------------
__global__ __launch_bounds__(256)
void pack_x_kernel(const float* __restrict__ x, u64* __restrict__ px) {
    int t = blockIdx.x * 256 + threadIdx.x;   // [0, 32*56*4*14) = 100352
    int w4   = t % 14;
    int r    = t / 14;
    int word = r & 3;
    int r2   = r >> 2;
    int h    = r2 % H;
    int n    = r2 / H;
    const float4* src = (const float4*)(x + ((size_t)(n*C_IN + word*64) * HW + h*W + w4*4));
    u64 b0 = 0, b1 = 0, b2 = 0, b3 = 0;
    #pragma unroll 8
    for (int j = 0; j < 64; ++j) {
        float4 v = src[(size_t)j * (HW/4)];
        b0 |= (u64)(__float_as_uint(v.x) >> 31) << j;
        b1 |= (u64)(__float_as_uint(v.y) >> 31) << j;
        b2 |= (u64)(__float_as_uint(v.z) >> 31) << j;
        b3 |= (u64)(__float_as_uint(v.w) >> 31) << j;
    }
    u64* dst = px + (((size_t)((n*H + h)*W + w4*4)) << 2) + word;
    dst[0] = b0; dst[4] = b1; dst[8] = b2; dst[12] = b3;
}

// ---------------------------------------------------------------------------
// Pack weights: pw2[word][co][tap] u64 — so the conv's (word, ci) inner step
// reads 9 contiguous u64 (72 B) -> s_load_dwordx16 + dwordx2.
// ---------------------------------------------------------------------------
__global__ __launch_bounds__(256)
void pack_w_kernel(const float* __restrict__ wt, u64* __restrict__ pw2) {
    int t = blockIdx.x * 256 + threadIdx.x;   // [0, 9216)
    int word = t / 2304;
    int rem  = t % 2304;
    int co   = rem / 9;
    int tap  = rem % 9;
    u64 bits = 0;
    for (int j = 0; j < 64; ++j) {
        int c = word*64 + j;
        float v = wt[((size_t)(co*C_IN + c) * 9) + tap];
        bits |= (u64)(__float_as_uint(v) >> 31) << j;
    }
    pw2[t] = bits;   // t == (word*256 + co)*9 + tap
}

// ---------------------------------------------------------------------------
// Main XNOR-popcount conv, interior-correct for ALL pixels (border pixels get
// garbage from clamp-free halo loads; conv_border overwrites them).
//
// Register-pressure-proof restructure (R3). R0-R2 history: holding 36 u64
// x-words across a 64-deep co loop needs 72+ VGPRs; the allocator is
// hard-committed to <=64 (launch_bounds(256,4) ignored; asm "+v" pins got
// SPILLED to scratch, VGPR=56, slower). Fix: word-outer / co-accumulator
// layout. Live set = acc[32] (32) + 9 x-words (18) + misc ~= 56 VGPRs.
// Fits <=64 BY CONSTRUCTION — nothing left for the allocator to fight.
// Per (ci,word,tap): 2 v_xor + 2 v_bcnt, mask-free. 4608 VALU/thread,
// 12544 waves -> ~47 us VALU floor.
// ---------------------------------------------------------------------------
__global__ __launch_bounds__(256)
void conv_main_kernel(const char* __restrict__ pxb, const u64* __restrict__ pw2,
                      short* __restrict__ y) {
    int p = blockIdx.x * 256 + threadIdx.x;   // pixel id [0, 100352)
    int n = p / HW;
    int r = p - n*HW;
    int cobase = blockIdx.y * 32;

    int acc[32];
    #pragma unroll
    for (int i = 0; i < 32; ++i) acc[i] = 0;

    const char* base = pxb + (size_t)p * 32;   // word0 of this pixel

    #pragma unroll 1
    for (int word = 0; word < 4; ++word) {
        const char* bw = base + word*8;
        // tap offsets: (dh*W + dw)*32 bytes = dh*1792 + dw*32, compile-time,
        // all within the 13-bit signed global_load immediate.
        u64 x0 = *(const u64*)(bw - 1792 - 32);
        u64 x1 = *(const u64*)(bw - 1792     );
        u64 x2 = *(const u64*)(bw - 1792 + 32);
        u64 x3 = *(const u64*)(bw        - 32);
        u64 x4 = *(const u64*)(bw            );
        u64 x5 = *(const u64*)(bw        + 32);
        u64 x6 = *(const u64*)(bw + 1792 - 32);
        u64 x7 = *(const u64*)(bw + 1792     );
        u64 x8 = *(const u64*)(bw + 1792 + 32);

        const u64* qw = pw2 + ((size_t)word*C_OUT + cobase)*9;  // wave-uniform
        #pragma unroll
        for (int ci = 0; ci < 32; ++ci) {
            const u64* q = qw + ci*9;
            int a = acc[ci];
            a += __popcll(x0 ^ q[0]);
            a += __popcll(x1 ^ q[1]);
            a += __popcll(x2 ^ q[2]);
            a += __popcll(x3 ^ q[3]);
            a += __popcll(x4 ^ q[4]);
            a += __popcll(x5 ^ q[5]);
            a += __popcll(x6 ^ q[6]);
            a += __popcll(x7 ^ q[7]);
            a += __popcll(x8 ^ q[8]);
            acc[ci] = a;
        }
    }

    short* yout = y + (size_t)n*CHW + (size_t)cobase*HW + r;
    #pragma unroll
    for (int ci = 0; ci < 32; ++ci)
        yout[(size_t)ci * HW] = (short)(2304 - 2*acc[ci]);
}

// ---------------------------------------------------------------------------
// Border fixup: the 220 border pixels per image (h==0 | h==55 | w==0 | w==55),
// computed exactly with per-tap validity masks. Same word-outer structure,
// acc[16] + co-chunks of 16 for enough waves (1792) to hide latency.
// y contribution of a valid tap = 256 - 2*popc4; invalid taps contribute 0:
// y = 256*n_valid - 2*acc.
// ---------------------------------------------------------------------------
__global__ __launch_bounds__(256)
void conv_border_kernel(const char* __restrict__ pxb, const u64* __restrict__ pw2,
                        short* __restrict__ y) {
    int i = blockIdx.x * 256 + threadIdx.x;   // [0, 7168) ; 7040 real
    if (i >= N_IMG * 220) return;
    int n = i / 220;
    int b = i % 220;
    int h, w;
    if (b < 56)       { h = 0;       w = b;       }
    else if (b < 112) { h = 55;      w = b - 56;  }
    else if (b < 166) { h = b - 111; w = 0;       }   // h in [1,54]
    else              { h = b - 165; w = 55;      }   // h in [1,54]
    int r = h*W + w;
    int p = n*HW + r;
    int cobase = blockIdx.y * 16;

    // per-tap validity
    int m[9], n_valid = 0;
    #pragma unroll
    for (int t = 0; t < 9; ++t) {
        int dh = t/3 - 1, dw = t%3 - 1;
        bool ok = ((unsigned)(h+dh) < (unsigned)H) && ((unsigned)(w+dw) < (unsigned)W);
        m[t] = ok ? -1 : 0;
        n_valid += ok ? 1 : 0;
    }

    int acc[16];
    #pragma unroll
    for (int k = 0; k < 16; ++k) acc[k] = 0;

    const char* base = pxb + (size_t)p * 32;

    #pragma unroll 1
    for (int word = 0; word < 4; ++word) {
        const char* bw = base + word*8;
        u64 x0 = *(const u64*)(bw - 1792 - 32);
        u64 x1 = *(const u64*)(bw - 1792     );
        u64 x2 = *(const u64*)(bw - 1792 + 32);
        u64 x3 = *(const u64*)(bw        - 32);
        u64 x4 = *(const u64*)(bw            );
        u64 x5 = *(const u64*)(bw        + 32);
        u64 x6 = *(const u64*)(bw + 1792 - 32);
        u64 x7 = *(const u64*)(bw + 1792     );
        u64 x8 = *(const u64*)(bw + 1792 + 32);

        const u64* qw = pw2 + ((size_t)word*C_OUT + cobase)*9;
        #pragma unroll
        for (int ci = 0; ci < 16; ++ci) {
            const u64* q = qw + ci*9;
            int a = acc[ci];
            a += __popcll(x0 ^ q[0]) & m[0];
            a += __popcll(x1 ^ q[1]) & m[1];
            a += __popcll(x2 ^ q[2]) & m[2];
            a += __popcll(x3 ^ q[3]) & m[3];
            a += __popcll(x4 ^ q[4]) & m[4];
            a += __popcll(x5 ^ q[5]) & m[5];
            a += __popcll(x6 ^ q[6]) & m[6];
            a += __popcll(x7 ^ q[7]) & m[7];
            a += __popcll(x8 ^ q[8]) & m[8];
            acc[ci] = a;
        }
    }

    short* yout = y + (size_t)n*CHW + (size_t)cobase*HW + r;
    #pragma unroll
    for (int ci = 0; ci < 16; ++ci)
        yout[(size_t)ci * HW] = (short)(256*n_valid - 2*acc[ci]);
}

// ---------------------------------------------------------------------------
// Stats pass: one block per (n,co) slab (3136 contiguous shorts), int4 loads,
// block-reduce, write per-slab partials.
// ---------------------------------------------------------------------------
__global__ __launch_bounds__(256)
void stats_kernel(const short* __restrict__ y, long long* __restrict__ partials) {
    int slab = blockIdx.x;                    // n*256 + co
    const int4* ys = (const int4*)(y + (size_t)slab * HW);
    int s = 0, sq = 0;
    for (int i = threadIdx.x; i < HW/8; i += 256) {
        int4 v = ys[i];
        int vv[4] = {v.x, v.y, v.z, v.w};
        #pragma unroll
        for (int k = 0; k < 4; ++k) {
            int lo = (short)(vv[k] & 0xFFFF);
            int hi = (short)(vv[k] >> 16);
            s  += lo + hi;
            sq += lo*lo + hi*hi;
        }
    }
    __shared__ int       rs[256];
    __shared__ long long rq[256];
    rs[threadIdx.x] = s;
    rq[threadIdx.x] = sq;
    __syncthreads();
    for (int off = 128; off > 0; off >>= 1) {
        if (threadIdx.x < off) {
            rs[threadIdx.x] += rs[threadIdx.x + off];
            rq[threadIdx.x] += rq[threadIdx.x + off];
        }
        __syncthreads();
    }
    if (threadIdx.x == 0) {
        partials[2*slab]   = rs[0];
        partials[2*slab+1] = rq[0];
    }
}

// ---------------------------------------------------------------------------
// Apply pass: one block per (n,co) slab.
// ---------------------------------------------------------------------------
__global__ __launch_bounds__(256)
void apply_kernel(const short* __restrict__ y, const long long* __restrict__ partials,
                  const float* __restrict__ gamma, const float* __restrict__ beta,
                  float* __restrict__ out) {
    int slab = blockIdx.x;
    int co = slab & 255;
    long long S = 0, SS = 0;
    #pragma unroll 8
    for (int m = 0; m < N_IMG; ++m) {
        S  += partials[2*((m<<8) | co)];
        SS += partials[2*((m<<8) | co) + 1];
    }
    double mean = (double)S  * (1.0 / (double)NHW);
    double var  = (double)SS * (1.0 / (double)NHW) - mean*mean;
    float a = gamma[co] * rsqrtf((float)var + 1e-5f);
    float b = beta[co] - (float)mean * a;

    const int4* ys = (const int4*)(y + (size_t)slab * HW);
    float4*     os = (float4*)(out + (size_t)slab * HW);
    for (int i = threadIdx.x; i < HW/8; i += 256) {
        int4 v = ys[i];
        float4 f0, f1;
        f0.x = a * (float)((short)(v.x & 0xFFFF)) + b;
        f0.y = a * (float)((short)(v.x >> 16))    + b;
        f0.z = a * (float)((short)(v.y & 0xFFFF)) + b;
        f0.w = a * (float)((short)(v.y >> 16))    + b;
        f1.x = a * (float)((short)(v.z & 0xFFFF)) + b;
        f1.y = a * (float)((short)(v.z >> 16))    + b;
        f1.z = a * (float)((short)(v.w & 0xFFFF)) + b;
        f1.w = a * (float)((short)(v.w >> 16))    + b;
        os[2*i]   = f0;
        os[2*i+1] = f1;
    }
}

// ---------------------------------------------------------------------------
extern "C" void kernel_launch(void* const* d_in, const int* in_sizes, int n_in,
                              void* d_out, int out_size, void* d_ws, size_t ws_size,
                              hipStream_t stream) {
    const float* x     = (const float*)d_in[0];
    const float* wt    = (const float*)d_in[1];
    const float* gamma = (const float*)d_in[2];
    const float* beta  = (const float*)d_in[3];
    float* out = (float*)d_out;

    char* ws = (char*)d_ws;
    u64*   px  = (u64*)(ws + PX_OFF);
    u64*   pw2 = (u64*)(ws + PW_OFF);
    short* y   = (short*)(ws + Y_OFF);
    long long* partials = (long long*)ws;   // overlaps pad+px: dead after border

    hipLaunchKernelGGL(pack_x_kernel,      dim3(100352/256), dim3(256), 0, stream, x, px);
    hipLaunchKernelGGL(pack_w_kernel,      dim3(9216/256),   dim3(256), 0, stream, wt, pw2);
    hipLaunchKernelGGL(conv_main_kernel,   dim3(392, 8),     dim3(256), 0, stream, (const char*)px, pw2, y);
    hipLaunchKernelGGL(conv_border_kernel, dim3(28, 16),     dim3(256), 0, stream, (const char*)px, pw2, y);
    hipLaunchKernelGGL(stats_kernel,       dim3(8192),       dim3(256), 0, stream, y, partials);
    hipLaunchKernelGGL(apply_kernel,       dim3(8192),       dim3(256), 0, stream, y, partials, gamma, beta, out);
}

// Round 4
// 319.341 us; speedup vs baseline: 1.2241x; 1.1608x over previous
//
#include <hip/hip_runtime.h>
#include <stdint.h>

typedef unsigned long long u64;
typedef unsigned int u32;
typedef int v4i  __attribute__((ext_vector_type(4)));
typedef int v16i __attribute__((ext_vector_type(16)));

#define N_IMG 32
#define C_IN  256
#define C_OUT 256
#define H     56
#define W     56
#define HW    (H*W)          // 3136
#define NHW   (N_IMG*HW)     // 100352
#define CHW   (C_IN*HW)      // 802816

// Workspace layout:
//   px  @ 0:        [n][h][w][4] u64 packed sign bits   (3,211,264 B)
//   wpk @ PX_BYTES: [tap][kb][co][32] i8 +-1 weights    (  589,824 B)
//   y   @ Y_OFF:    [n][co][h][w] int16 conv result     (51,380,224 B)
//   partials overlaps px (px dead after conv)
#define PX_BYTES  3211264
#define WPK_BYTES 589824
#define Y_OFF     (PX_BYTES + WPK_BYTES)

// ---------------------------------------------------------------------------
// Pack activations (UNCHANGED, known-good). bit=1 <=> sign(x)==-1.
// ---------------------------------------------------------------------------
__global__ __launch_bounds__(256)
void pack_x_kernel(const float* __restrict__ x, u64* __restrict__ px) {
    int t = blockIdx.x * 256 + threadIdx.x;   // [0, 100352)
    int w4   = t % 14;
    int r    = t / 14;
    int word = r & 3;
    int r2   = r >> 2;
    int h    = r2 % H;
    int n    = r2 / H;
    const float4* src = (const float4*)(x + ((size_t)(n*C_IN + word*64) * HW + h*W + w4*4));
    u64 b0 = 0, b1 = 0, b2 = 0, b3 = 0;
    #pragma unroll 8
    for (int j = 0; j < 64; ++j) {
        float4 v = src[(size_t)j * (HW/4)];
        b0 |= (u64)(__float_as_uint(v.x) >> 31) << j;
        b1 |= (u64)(__float_as_uint(v.y) >> 31) << j;
        b2 |= (u64)(__float_as_uint(v.z) >> 31) << j;
        b3 |= (u64)(__float_as_uint(v.w) >> 31) << j;
    }
    u64* dst = px + (((size_t)((n*H + h)*W + w4*4)) << 2) + word;
    dst[0] = b0; dst[4] = b1; dst[8] = b2; dst[12] = b3;
}

// ---------------------------------------------------------------------------
// Pack weights as +-1 int8, MFMA-A-fragment-friendly layout:
//   wpk[((tap*8 + kb)*256 + co)*32 + kk] = sign byte of w[co][ci=kb*32+kk][tap]
// (0x01 = +1, 0xFF = -1). Lane l of a wave reads 16 B at co=cot+(l&31),
// half=(l>>5) -> contiguous 1KB per wave -> perfectly coalesced.
// ---------------------------------------------------------------------------
__global__ __launch_bounds__(256)
void pack_wpk_kernel(const float* __restrict__ wt, char* __restrict__ wpk) {
    int t = blockIdx.x * 256 + threadIdx.x;   // [0, 18432) = (tap*8+kb)*256+co
    int co = t & 255;
    int tk = t >> 8;          // 0..71
    int tap = tk >> 3;
    int kb  = tk & 7;
    u32* out = (u32*)wpk + t*8;
    #pragma unroll
    for (int g = 0; g < 8; ++g) {
        u32 dw = 0;
        #pragma unroll
        for (int b = 0; b < 4; ++b) {
            int ci = kb*32 + 4*g + b;
            float v = wt[((size_t)(co*C_IN + ci)) * 9 + tap];
            u32 byte = (__float_as_uint(v) >> 31) ? 0xFFu : 0x01u;
            dw |= byte << (8*b);
        }
        out[g] = dw;
    }
}

// ---------------------------------------------------------------------------
// MFMA conv (R4). Popcount path is dead: R3 measured 115us of VALU issue vs a
// 47us 2cy/inst model -> v_bcnt is ~quarter-rate on gfx950; matrix pipe sat
// at MfmaUtil=0 all session. This kernel does the 59.2G MACs on the i8 MFMA
// pipe (~27us floor at 4404 TOPS).
//
//   D[32co x 32px] += A[32co x 32k] * B[32k x 32px],  v_mfma_i32_32x32x32_i8
//   A: weights +-1 i8 from global (L2-resident, 1KB/wave coalesced frags)
//   B: activations expanded bit->i8 (+1/-1, 0 for padding!) into LDS.
//      Padding handled by ZERO bytes -> no border kernel, exact conv.
//
// Block: 2 output rows x 128 co. 4 waves; wave = 32 co x 4 px-tiles (112 px
// + 16 discarded). K-loop: 9 taps x 8 ci-blocks = 72 steps, 4 MFMA each.
// LDS [4 rows][66 w'][256 ci] i8, XOR-swizzled at 16B granularity with
// (w'&15)<<4 so the stride-256 column reads spread over all 8 bank-quads.
//
// Fragment maps (guide-verified on gfx950):
//   A: m=lane&31 (co), k=16*(lane>>5)+e ; B: n=lane&31 (px), same k
//   C/D: col(px)=lane&31, row(co)=(reg&3)+8*(reg>>2)+4*(lane>>5)
// ---------------------------------------------------------------------------
__global__ __launch_bounds__(256, 2)
void conv_mfma_kernel(const u64* __restrict__ px, const char* __restrict__ wpk,
                      short* __restrict__ y) {
    __shared__ char lds[4*66*256];            // 67,584 B -> 2 blocks/CU
    int bx = blockIdx.x;                      // [0, 896) = n*28 + hp
    int n  = bx / 28;
    int h0 = (bx % 28) * 2;
    int cobase = blockIdx.y * 128;
    int tid = threadIdx.x;

    // ---- stage: expand packed bits -> i8 into swizzled LDS ----
    for (int i = tid; i < 4*66; i += 256) {   // (row, w') pairs
        int row = i / 66;
        int wp  = i % 66;
        int hh = h0 + row - 1;
        int ww = wp - 1;
        bool valid = ((unsigned)hh < (unsigned)H) && ((unsigned)ww < (unsigned)W);
        u64 wv0 = 0, wv1 = 0, wv2 = 0, wv3 = 0;
        if (valid) {
            const u64* s = px + (((size_t)((n*H + hh)*W + ww)) << 2);
            wv0 = s[0]; wv1 = s[1]; wv2 = s[2]; wv3 = s[3];
        }
        u32 basev = valid ? 0x01010101u : 0u;  // padding stays 0x00
        char* out = lds + i*256;
        int sw = (wp & 15) << 4;
        u64 wvs[4] = {wv0, wv1, wv2, wv3};
        #pragma unroll
        for (int c4 = 0; c4 < 16; ++c4) {
            u32 bits = (u32)(wvs[c4>>2] >> ((c4&3)*16)) & 0xFFFFu;
            v4i ov;
            #pragma unroll
            for (int d = 0; d < 4; ++d) {
                u32 sel = (bits >> (4*d)) & 0xFu;
                u32 sp  = (sel * 0x204081u) & 0x01010101u;  // bit i -> byte i
                u32 m   = (sp << 8) - (sp << 1);            // 0xFE per set byte
                ov[d] = (int)(basev + m);                   // 0xFF(-1)/0x01(+1)/0x00(pad)
            }
            *(v4i*)(out + ((c4*16) ^ sw)) = ov;
        }
    }
    __syncthreads();

    int wid  = tid >> 6;
    int lane = tid & 63;
    int l31  = lane & 31;
    int lhalf = lane >> 5;
    int lh16 = lhalf << 4;
    int cot  = cobase + wid*32;

    // px-tile lane geometry: tile j covers strip pixels j*32+l31
    // strip px: 0..55 -> row h0, 56..111 -> row h0+1, 112..127 garbage
    int p1 = 32 + l31, p3 = 96 + l31;
    int hr1 = (p1 >= 56);
    int wl0 = l31;
    int wl1 = p1 - (hr1 ? 56 : 0);
    int wl2 = (64 + l31) - 56;
    int wl3a = p3 - 56; int wl3 = wl3a > 55 ? 55 : wl3a;   // clamp garbage lanes
    int rb0 = 0, rb1 = hr1 * (66*256), rb2 = 66*256, rb3 = 66*256;

    v16i acc0 = {0,0,0,0,0,0,0,0,0,0,0,0,0,0,0,0};
    v16i acc1 = acc0, acc2 = acc0, acc3 = acc0;

    const v4i* wq = (const v4i*)wpk;

    #pragma unroll
    for (int tap = 0; tap < 9; ++tap) {
        const int dw  = tap % 3;
        const int rof = (tap / 3) * (66*256);
        int wp0 = wl0 + dw, wp1 = wl1 + dw, wp2 = wl2 + dw, wp3 = wl3 + dw;
        int sw0 = (wp0 & 15) << 4, sw1 = (wp1 & 15) << 4;
        int sw2 = (wp2 & 15) << 4, sw3 = (wp3 & 15) << 4;
        int a0 = rb0 + rof + wp0*256;
        int a1 = rb1 + rof + wp1*256;
        int a2 = rb2 + rof + wp2*256;
        int a3 = rb3 + rof + wp3*256;
        #pragma unroll
        for (int kb = 0; kb < 8; ++kb) {
            v4i av = wq[(((tap*8 + kb)*256 + cot + l31) << 1) | lhalf];
            int kof = kb*32 + lh16;
            v4i b0 = *(const v4i*)(lds + a0 + (kof ^ sw0));
            v4i b1 = *(const v4i*)(lds + a1 + (kof ^ sw1));
            v4i b2 = *(const v4i*)(lds + a2 + (kof ^ sw2));
            v4i b3 = *(const v4i*)(lds + a3 + (kof ^ sw3));
            acc0 = __builtin_amdgcn_mfma_i32_32x32x32_i8(av, b0, acc0, 0, 0, 0);
            acc1 = __builtin_amdgcn_mfma_i32_32x32x32_i8(av, b1, acc1, 0, 0, 0);
            acc2 = __builtin_amdgcn_mfma_i32_32x32x32_i8(av, b2, acc2, 0, 0, 0);
            acc3 = __builtin_amdgcn_mfma_i32_32x32x32_i8(av, b3, acc3, 0, 0, 0);
        }
    }

    // ---- store: lanes = consecutive px (64B runs); tile 3 masked ----
    size_t ybase = (size_t)n*CHW + (size_t)(cot + (lhalf << 2))*HW;
    {
        size_t o = ybase + (size_t)(h0 + 0)*W + wl0;
        #pragma unroll
        for (int rg = 0; rg < 16; ++rg)
            y[o + (size_t)((rg&3) + 8*(rg>>2))*HW] = (short)acc0[rg];
    }
    {
        size_t o = ybase + (size_t)(h0 + hr1)*W + wl1;
        #pragma unroll
        for (int rg = 0; rg < 16; ++rg)
            y[o + (size_t)((rg&3) + 8*(rg>>2))*HW] = (short)acc1[rg];
    }
    {
        size_t o = ybase + (size_t)(h0 + 1)*W + wl2;
        #pragma unroll
        for (int rg = 0; rg < 16; ++rg)
            y[o + (size_t)((rg&3) + 8*(rg>>2))*HW] = (short)acc2[rg];
    }
    if (l31 < 16) {
        size_t o = ybase + (size_t)(h0 + 1)*W + wl3;
        #pragma unroll
        for (int rg = 0; rg < 16; ++rg)
            y[o + (size_t)((rg&3) + 8*(rg>>2))*HW] = (short)acc3[rg];
    }
}

// ---------------------------------------------------------------------------
// Stats pass (UNCHANGED): one block per (n,co) slab.
// ---------------------------------------------------------------------------
__global__ __launch_bounds__(256)
void stats_kernel(const short* __restrict__ y, long long* __restrict__ partials) {
    int slab = blockIdx.x;                    // n*256 + co
    const int4* ys = (const int4*)(y + (size_t)slab * HW);
    int s = 0, sq = 0;
    for (int i = threadIdx.x; i < HW/8; i += 256) {
        int4 v = ys[i];
        int vv[4] = {v.x, v.y, v.z, v.w};
        #pragma unroll
        for (int k = 0; k < 4; ++k) {
            int lo = (short)(vv[k] & 0xFFFF);
            int hi = (short)(vv[k] >> 16);
            s  += lo + hi;
            sq += lo*lo + hi*hi;
        }
    }
    __shared__ int       rs[256];
    __shared__ long long rq[256];
    rs[threadIdx.x] = s;
    rq[threadIdx.x] = sq;
    __syncthreads();
    for (int off = 128; off > 0; off >>= 1) {
        if (threadIdx.x < off) {
            rs[threadIdx.x] += rs[threadIdx.x + off];
            rq[threadIdx.x] += rq[threadIdx.x + off];
        }
        __syncthreads();
    }
    if (threadIdx.x == 0) {
        partials[2*slab]   = rs[0];
        partials[2*slab+1] = rq[0];
    }
}

// ---------------------------------------------------------------------------
// Apply pass (UNCHANGED): one block per (n,co) slab.
// ---------------------------------------------------------------------------
__global__ __launch_bounds__(256)
void apply_kernel(const short* __restrict__ y, const long long* __restrict__ partials,
                  const float* __restrict__ gamma, const float* __restrict__ beta,
                  float* __restrict__ out) {
    int slab = blockIdx.x;
    int co = slab & 255;
    long long S = 0, SS = 0;
    #pragma unroll 8
    for (int m = 0; m < N_IMG; ++m) {
        S  += partials[2*((m<<8) | co)];
        SS += partials[2*((m<<8) | co) + 1];
    }
    double mean = (double)S  * (1.0 / (double)NHW);
    double var  = (double)SS * (1.0 / (double)NHW) - mean*mean;
    float a = gamma[co] * rsqrtf((float)var + 1e-5f);
    float b = beta[co] - (float)mean * a;

    const int4* ys = (const int4*)(y + (size_t)slab * HW);
    float4*     os = (float4*)(out + (size_t)slab * HW);
    for (int i = threadIdx.x; i < HW/8; i += 256) {
        int4 v = ys[i];
        float4 f0, f1;
        f0.x = a * (float)((short)(v.x & 0xFFFF)) + b;
        f0.y = a * (float)((short)(v.x >> 16))    + b;
        f0.z = a * (float)((short)(v.y & 0xFFFF)) + b;
        f0.w = a * (float)((short)(v.y >> 16))    + b;
        f1.x = a * (float)((short)(v.z & 0xFFFF)) + b;
        f1.y = a * (float)((short)(v.z >> 16))    + b;
        f1.z = a * (float)((short)(v.w & 0xFFFF)) + b;
        f1.w = a * (float)((short)(v.w >> 16))    + b;
        os[2*i]   = f0;
        os[2*i+1] = f1;
    }
}

// ---------------------------------------------------------------------------
extern "C" void kernel_launch(void* const* d_in, const int* in_sizes, int n_in,
                              void* d_out, int out_size, void* d_ws, size_t ws_size,
                              hipStream_t stream) {
    const float* x     = (const float*)d_in[0];
    const float* wt    = (const float*)d_in[1];
    const float* gamma = (const float*)d_in[2];
    const float* beta  = (const float*)d_in[3];
    float* out = (float*)d_out;

    char* ws = (char*)d_ws;
    u64*   px  = (u64*)ws;
    char*  wpk = ws + PX_BYTES;
    short* y   = (short*)(ws + Y_OFF);
    long long* partials = (long long*)ws;   // overlaps px: px dead after conv

    hipLaunchKernelGGL(pack_x_kernel,   dim3(100352/256), dim3(256), 0, stream, x, px);
    hipLaunchKernelGGL(pack_wpk_kernel, dim3(72),         dim3(256), 0, stream, wt, wpk);
    hipLaunchKernelGGL(conv_mfma_kernel,dim3(896, 2),     dim3(256), 0, stream, px, wpk, y);
    hipLaunchKernelGGL(stats_kernel,    dim3(8192),       dim3(256), 0, stream, y, partials);
    hipLaunchKernelGGL(apply_kernel,    dim3(8192),       dim3(256), 0, stream, y, partials, gamma, beta, out);
}